// Round 6
// baseline (883.141 us; speedup 1.0000x reference)
//
#include <hip/hip_runtime.h>
#include <hip/hip_bf16.h>

// ---------------------------------------------------------------------------
// PlanStructuredNetwork — round 8.
//   R7 post-mortem: occupancy pinned at 40% regardless of VGPR/bounds ->
//   NOT VGPR-limited. bias-LDS added ~19% LDS traffic -> leaf 159->170.
//   LDS-byte model: leaf runs the LDS pipe ~76% busy => LDS-BW-bound.
//   R8 (leaf only): 64-row tiles, 2x2 wave grid (Wm=2 M-halves x Wn=2
//   row-halves). Each wave reads B-operands only for its 32-row half ->
//   L1/L2 LDS read amplification halves (~-35-40% traffic/row). MFMA/row,
//   HBM/row unchanged. VGPR ~160 (3 waves/SIMD), LDS 49 KB (3 blocks/CU)
//   = today's achieved 12 waves/CU, so nothing lost if LDS-BW theory holds.
//   * joins: EXACT R3-verified structure (32-row, bias regs, vmcnt(2)).
//   * tail: fused levels 16..1 (R5/R7-verified).
//   * leaf vmcnt: steady queue [stage_t:2][stores:2][stage_{t+1}:2] ->
//     uniform vmcnt(2) (drains stage_t+stores, keeps prefetch in flight).
// ws: 114688 B weights + 128 MB curA + 64 MB curB (~192.1 MB).
// ---------------------------------------------------------------------------

typedef _Float16 f16;
typedef _Float16 f16x8 __attribute__((ext_vector_type(8)));
typedef _Float16 f16x4 __attribute__((ext_vector_type(4)));
typedef float    f32x4 __attribute__((ext_vector_type(4)));

#define MFMA16(a, b, c) __builtin_amdgcn_mfma_f32_16x16x32_f16((a), (b), (c), 0, 0, 0)
#define LGKM0    asm volatile("s_waitcnt lgkmcnt(0)" ::: "memory")

// ws element offsets (f16) of transposed weights W^T[m][k]
#define OFF_S1 0       // [128][32]
#define OFF_S2 4096    // [128][128]
#define OFF_S3 20480   // [32][128]
#define OFF_J1 24576   // [128][96]
#define OFF_J2 36864   // [128][128]
#define OFF_J3 53248   // [32][128]
#define W_TOTAL 57344
#define CURA_BYTE_OFF 114688   // = W_TOTAL*2

__global__ void prep_weights(const float* __restrict__ sW1,
                             const float* __restrict__ sW2,
                             const float* __restrict__ sW3,
                             const float* __restrict__ jW1,
                             const float* __restrict__ jW2,
                             const float* __restrict__ jW3,
                             f16* __restrict__ wbuf)
{
    int idx = blockIdx.x * 256 + threadIdx.x;
    if (idx >= W_TOTAL) return;
    const float* W;
    int off, M, K;
    if (idx < OFF_S2)      { off = OFF_S1; M = 128; K = 32;  W = sW1; }
    else if (idx < OFF_S3) { off = OFF_S2; M = 128; K = 128; W = sW2; }
    else if (idx < OFF_J1) { off = OFF_S3; M = 32;  K = 128; W = sW3; }
    else if (idx < OFF_J2) { off = OFF_J1; M = 128; K = 96;  W = jW1; }
    else if (idx < OFF_J3) { off = OFF_J2; M = 128; K = 128; W = jW2; }
    else                   { off = OFF_J3; M = 32;  K = 128; W = jW3; }
    int r = idx - off;
    int m = r / K;
    int k = r - m * K;
    wbuf[idx] = (f16)W[(size_t)k * M + m];   // W^T[m][k] = W[k][m]
}

__device__ __forceinline__ void gload16(const void* g, void* l)
{
    // async global->LDS, 16 B/lane; LDS dest = wave-uniform base + lane*16
    __builtin_amdgcn_global_load_lds(
        (const __attribute__((address_space(1))) void*)g,
        (__attribute__((address_space(3))) void*)l,
        16, 0, 0);
}

// ---------------------------------------------------------------------------
// LEAF: 64-row tiles, 2x2 wave grid. Wave (wm = wave>>1, wn = wave&1):
//   L1/L2: M-rows [64wm, 64wm+64), data rows [32wn, 32wn+32) (2 groups of 16)
//   L3 (M=32): M-rows [16wm, 16wm+16), data rows [32wn, 32wn+32)
// h rows: 128 f16 = 256 B = 16 chunks of 16B; chunk XOR-swizzled by row&7.
// ---------------------------------------------------------------------------
__global__ __launch_bounds__(256, 3)
void mlp_leaf64(const float* __restrict__ feats,
                f16*         __restrict__ cur_out,
                const f16*   __restrict__ W1t,
                const f16*   __restrict__ W2t,
                const f16*   __restrict__ W3t,
                const float* __restrict__ b1,
                const float* __restrict__ b2,
                const float* __restrict__ b3,
                int nt)
{
    __shared__ __align__(16) f16   h1[64 * 128];          // 16 KB
    __shared__ __align__(16) f16   h2[64 * 128];          // 16 KB
    __shared__ __align__(16) float fstage[2][64 * 32];    // 2 x 8 KB
    __shared__ __align__(16) float bias_lds[288];

    const int tid  = threadIdx.x;
    const int wave = tid >> 6;
    const int lane = tid & 63;
    const int n    = lane & 15;
    const int q    = lane >> 4;
    const int n7   = n & 7;
    const int wm   = wave >> 1;   // M-half
    const int wn   = wave & 1;    // data-row half

    // staging: wave stages rows [16w,16w+16) in 2 gloads of 8 rows; LDS dest
    // linear, source chunk pre-swizzled: slot s of row r holds chunk s^(r&7).
    const int schunk = (lane & 7) ^ (lane >> 3);

    if (tid < 128) bias_lds[tid] = b1[tid];
    else           bias_lds[tid] = b2[tid - 128];
    if (tid < 32)  bias_lds[256 + tid] = b3[tid];

    // resident weights: A[m][k]: lane (n,q) holds k = 32ks+8q..+7 of row m
    f16x8 A1[4], A2[4][4], A3[4];
#pragma unroll
    for (int mt = 0; mt < 4; ++mt)
        A1[mt] = *(const f16x8*)(W1t + (size_t)(64 * wm + 16 * mt + n) * 32 + 8 * q);
#pragma unroll
    for (int mt = 0; mt < 4; ++mt)
#pragma unroll
        for (int ks = 0; ks < 4; ++ks)
            A2[mt][ks] = *(const f16x8*)(W2t + (size_t)(64 * wm + 16 * mt + n) * 128 + 32 * ks + 8 * q);
#pragma unroll
    for (int ks = 0; ks < 4; ++ks)
        A3[ks] = *(const f16x8*)(W3t + (size_t)(16 * wm + n) * 128 + 32 * ks + 8 * q);

    auto stage = [&](int tg0, int sb) {
#pragma unroll
        for (int half = 0; half < 2; ++half) {
            int gr = tg0 + 16 * wave + 8 * half + (lane >> 3);
            gload16(feats + (size_t)gr * 32 + schunk * 4,
                    &fstage[sb][wave * 512 + half * 256]);
        }
    };

    const int stride = gridDim.x * 64;
    int g0 = blockIdx.x * 64;
    int rb = 0;
    stage(g0, 0);                 // prologue: tile 0 in flight (2 ops)
    LGKM0;                        // bias ds_writes drained pre-barrier

    for (int t = 0; t < nt; ++t, g0 += stride) {
        stage(t + 1 < nt ? g0 + stride : g0, rb ^ 1);
        // steady queue: [stage_t:2][stores_{t-1}:2][stage_{t+1}:2] -> 2 ok
        asm volatile("s_waitcnt vmcnt(2)" ::: "memory");
        __builtin_amdgcn_s_barrier();

        // ---------------- layer 1 ----------------
        f32x4 C[2][4];
#pragma unroll
        for (int mt = 0; mt < 4; ++mt) {
            f32x4 bv = *(const f32x4*)&bias_lds[64 * wm + 16 * mt + 4 * q];
            C[0][mt] = bv; C[1][mt] = bv;
        }
#pragma unroll
        for (int g = 0; g < 2; ++g) {
            const int r = 32 * wn + 16 * g + n;     // r&7 == n7
            f32x4 fa = *(const f32x4*)&fstage[rb][r * 32 + (((2 * q)     ^ n7) << 2)];
            f32x4 fb = *(const f32x4*)&fstage[rb][r * 32 + (((2 * q + 1) ^ n7) << 2)];
            f16x8 Bf;
#pragma unroll
            for (int j = 0; j < 4; ++j) { Bf[j] = (f16)fa[j]; Bf[4 + j] = (f16)fb[j]; }
#pragma unroll
            for (int mt = 0; mt < 4; ++mt) C[g][mt] = MFMA16(A1[mt], Bf, C[g][mt]);
        }
        // relu+pack -> h1[row][m], m = 64wm+16mt+4q+reg; chunk = m>>3, swz ^n7
#pragma unroll
        for (int g = 0; g < 2; ++g)
#pragma unroll
            for (int mt = 0; mt < 4; ++mt) {
                f16x4 pk;
                pk[0] = (f16)fmaxf(C[g][mt][0], 0.0f);
                pk[1] = (f16)fmaxf(C[g][mt][1], 0.0f);
                pk[2] = (f16)fmaxf(C[g][mt][2], 0.0f);
                pk[3] = (f16)fmaxf(C[g][mt][3], 0.0f);
                const int c = 8 * wm + 2 * mt + (q >> 1);
                *(f16x4*)&h1[(32 * wn + 16 * g + n) * 128 + ((c ^ n7) << 3) + 4 * (q & 1)] = pk;
            }
        LGKM0;
        __builtin_amdgcn_s_barrier();

        // ---------------- layer 2 ----------------
#pragma unroll
        for (int mt = 0; mt < 4; ++mt) {
            f32x4 bv = *(const f32x4*)&bias_lds[128 + 64 * wm + 16 * mt + 4 * q];
            C[0][mt] = bv; C[1][mt] = bv;
        }
#pragma unroll
        for (int ks = 0; ks < 4; ++ks)
#pragma unroll
            for (int g = 0; g < 2; ++g) {
                const int r = 32 * wn + 16 * g + n;
                f16x8 Bf = *(const f16x8*)&h1[r * 128 + (((4 * ks + q) ^ n7) << 3)];
#pragma unroll
                for (int mt = 0; mt < 4; ++mt) C[g][mt] = MFMA16(A2[mt][ks], Bf, C[g][mt]);
            }
#pragma unroll
        for (int g = 0; g < 2; ++g)
#pragma unroll
            for (int mt = 0; mt < 4; ++mt) {
                f16x4 pk;
                pk[0] = (f16)fmaxf(C[g][mt][0], 0.0f);
                pk[1] = (f16)fmaxf(C[g][mt][1], 0.0f);
                pk[2] = (f16)fmaxf(C[g][mt][2], 0.0f);
                pk[3] = (f16)fmaxf(C[g][mt][3], 0.0f);
                const int c = 8 * wm + 2 * mt + (q >> 1);
                *(f16x4*)&h2[(32 * wn + 16 * g + n) * 128 + ((c ^ n7) << 3) + 4 * (q & 1)] = pk;
            }
        LGKM0;
        __builtin_amdgcn_s_barrier();

        // ---------------- layer 3 (M-rows [16wm,16wm+16)) ----------------
        f32x4 C3[2];
        {
            f32x4 bv = *(const f32x4*)&bias_lds[256 + 16 * wm + 4 * q];
            C3[0] = bv; C3[1] = bv;
        }
#pragma unroll
        for (int g = 0; g < 2; ++g)
#pragma unroll
            for (int ks = 0; ks < 4; ++ks) {
                const int r = 32 * wn + 16 * g + n;
                f16x8 Bf = *(const f16x8*)&h2[r * 128 + (((4 * ks + q) ^ n7) << 3)];
                C3[g] = MFMA16(A3[ks], Bf, C3[g]);
            }
#pragma unroll
        for (int g = 0; g < 2; ++g) {
            f16x4 pk;
            pk[0] = (f16)C3[g][0]; pk[1] = (f16)C3[g][1];
            pk[2] = (f16)C3[g][2]; pk[3] = (f16)C3[g][3];
            *(f16x4*)(cur_out + (size_t)(g0 + 32 * wn + 16 * g + n) * 32 + 16 * wm + 4 * q) = pk;
        }
        rb ^= 1;
    }
}

// ---------------------------------------------------------------------------
// JOIN: EXACT R3-verified structure (32-row tiles, 4-way M-split, bias regs).
// ---------------------------------------------------------------------------
__global__ __launch_bounds__(256, 3)
void mlp_join(const float* __restrict__ feats,
              const f16*   __restrict__ cur_in,
              f16*         __restrict__ cur_out,
              const f16*   __restrict__ W1t,
              const f16*   __restrict__ W2t,
              const f16*   __restrict__ W3t,
              const float* __restrict__ b1,
              const float* __restrict__ b2,
              const float* __restrict__ b3,
              int rows, int log2n, int foff)
{
    constexpr int K1    = 96;
    constexpr int PITCH = 136;

    __shared__ __align__(16) f16   h1[32 * PITCH];
    __shared__ __align__(16) f16   h2[32 * PITCH];
    __shared__ __align__(16) float fstage[2][32 * 32];
    __shared__ __align__(16) f16   cstage[2][32 * 64];

    const int tid  = threadIdx.x;
    const int wave = tid >> 6;
    const int lane = tid & 63;
    const int n    = lane & 15;
    const int q    = lane >> 4;
    const int n7   = n & 7;
    const int mrow = 32 * wave;
    const int l3g  = wave & 1;
    const int l3h  = wave >> 1;

    const int srow   = (wave << 3) + (lane >> 3);
    const int schunk = (lane & 7) ^ (lane >> 3);

    f16x8 A1[2][3], A2[2][4], A3[4];
#pragma unroll
    for (int mt = 0; mt < 2; ++mt)
#pragma unroll
        for (int ks = 0; ks < 3; ++ks)
            A1[mt][ks] = *(const f16x8*)(W1t + (size_t)(mrow + 16 * mt + n) * K1 + 32 * ks + 8 * q);
#pragma unroll
    for (int mt = 0; mt < 2; ++mt)
#pragma unroll
        for (int ks = 0; ks < 4; ++ks)
            A2[mt][ks] = *(const f16x8*)(W2t + (size_t)(mrow + 16 * mt + n) * 128 + 32 * ks + 8 * q);
#pragma unroll
    for (int ks = 0; ks < 4; ++ks)
        A3[ks] = *(const f16x8*)(W3t + (size_t)(16 * l3h + n) * 128 + 32 * ks + 8 * q);

    f32x4 bf1[2], bf2[2], bf3;
#pragma unroll
    for (int mt = 0; mt < 2; ++mt) {
        bf1[mt] = *(const f32x4*)(b1 + mrow + 16 * mt + 4 * q);
        bf2[mt] = *(const f32x4*)(b2 + mrow + 16 * mt + 4 * q);
    }
    bf3 = *(const f32x4*)(b3 + 16 * l3h + 4 * q);

    auto stage = [&](int tg0, int sb) {
        int gr = tg0 + srow;
        int bb = gr >> log2n;
        int ii = gr & ((1 << log2n) - 1);
        const float* fsrc = feats + ((size_t)bb * 1023 + foff + ii) * 32 + schunk * 4;
        gload16(fsrc, &fstage[sb][wave * 256]);
        gload16(cur_in + (size_t)gr * 64 + schunk * 8, &cstage[sb][wave * 512]);
    };

    const int stride = gridDim.x * 32;
    int g0 = blockIdx.x * 32;
    if (g0 >= rows) return;

    int rb = 0;
    stage(g0, 0);

    for (; g0 < rows; g0 += stride) {
        int gnext = g0 + stride;
        stage(gnext < rows ? gnext : g0, rb ^ 1);

        asm volatile("s_waitcnt vmcnt(2)" ::: "memory");
        __builtin_amdgcn_s_barrier();

        // layer 1
        f32x4 C[2][2];
#pragma unroll
        for (int g = 0; g < 2; ++g)
#pragma unroll
            for (int mt = 0; mt < 2; ++mt) C[g][mt] = bf1[mt];

#pragma unroll
        for (int g = 0; g < 2; ++g) {
            const int r = 16 * g + n;
            f32x4 fa = *(const f32x4*)(&fstage[rb][r * 32 + (((2 * q)     ^ n7) * 4)]);
            f32x4 fb = *(const f32x4*)(&fstage[rb][r * 32 + (((2 * q + 1) ^ n7) * 4)]);
            f16x8 Bf;
#pragma unroll
            for (int j = 0; j < 4; ++j) { Bf[j] = (f16)fa[j]; Bf[4 + j] = (f16)fb[j]; }
#pragma unroll
            for (int mt = 0; mt < 2; ++mt) C[g][mt] = MFMA16(A1[mt][0], Bf, C[g][mt]);
            f16x8 cl = *(const f16x8*)(&cstage[rb][r * 64 + ((q       ^ n7) * 8)]);
            f16x8 cr = *(const f16x8*)(&cstage[rb][r * 64 + (((4 + q) ^ n7) * 8)]);
#pragma unroll
            for (int mt = 0; mt < 2; ++mt) C[g][mt] = MFMA16(A1[mt][1], cl, C[g][mt]);
#pragma unroll
            for (int mt = 0; mt < 2; ++mt) C[g][mt] = MFMA16(A1[mt][2], cr, C[g][mt]);
        }
#pragma unroll
        for (int g = 0; g < 2; ++g)
#pragma unroll
            for (int mt = 0; mt < 2; ++mt) {
                f16x4 pk;
                pk[0] = (f16)fmaxf(C[g][mt][0], 0.0f);
                pk[1] = (f16)fmaxf(C[g][mt][1], 0.0f);
                pk[2] = (f16)fmaxf(C[g][mt][2], 0.0f);
                pk[3] = (f16)fmaxf(C[g][mt][3], 0.0f);
                *(f16x4*)(h1 + (16 * g + n) * PITCH + mrow + 16 * mt + 4 * q) = pk;
            }
        LGKM0;
        __builtin_amdgcn_s_barrier();

        // layer 2
#pragma unroll
        for (int g = 0; g < 2; ++g)
#pragma unroll
            for (int mt = 0; mt < 2; ++mt) C[g][mt] = bf2[mt];
#pragma unroll
        for (int ks = 0; ks < 4; ++ks)
#pragma unroll
            for (int g = 0; g < 2; ++g) {
                f16x8 Bf = *(const f16x8*)(h1 + (16 * g + n) * PITCH + 32 * ks + 8 * q);
#pragma unroll
                for (int mt = 0; mt < 2; ++mt) C[g][mt] = MFMA16(A2[mt][ks], Bf, C[g][mt]);
            }
#pragma unroll
        for (int g = 0; g < 2; ++g)
#pragma unroll
            for (int mt = 0; mt < 2; ++mt) {
                f16x4 pk;
                pk[0] = (f16)fmaxf(C[g][mt][0], 0.0f);
                pk[1] = (f16)fmaxf(C[g][mt][1], 0.0f);
                pk[2] = (f16)fmaxf(C[g][mt][2], 0.0f);
                pk[3] = (f16)fmaxf(C[g][mt][3], 0.0f);
                *(f16x4*)(h2 + (16 * g + n) * PITCH + mrow + 16 * mt + 4 * q) = pk;
            }
        LGKM0;
        __builtin_amdgcn_s_barrier();

        // layer 3
        f32x4 C3 = bf3;
#pragma unroll
        for (int ks = 0; ks < 4; ++ks) {
            f16x8 Bf = *(const f16x8*)(h2 + (16 * l3g + n) * PITCH + 32 * ks + 8 * q);
            C3 = MFMA16(A3[ks], Bf, C3);
        }
        {
            f16x4 pk;
            pk[0] = (f16)C3[0]; pk[1] = (f16)C3[1]; pk[2] = (f16)C3[2]; pk[3] = (f16)C3[3];
            *(f16x4*)(cur_out + (size_t)(g0 + 16 * l3g + n) * 32 + 16 * l3h + 4 * q) = pk;
        }
        rb ^= 1;
    }
}

// ---- fused tail: levels nlev=16,8,4,2,1 for 2 batches per block -----------
__global__ __launch_bounds__(256, 2)
void mlp_tail(const float* __restrict__ feats,
              const f16*   __restrict__ cur_in,
              float*       __restrict__ out_final,
              const f16*   __restrict__ W1t,
              const f16*   __restrict__ W2t,
              const f16*   __restrict__ W3t,
              const float* __restrict__ b1,
              const float* __restrict__ b2,
              const float* __restrict__ b3)
{
    __shared__ __align__(16) f16   h1[32 * 128];
    __shared__ __align__(16) f16   h2[32 * 128];
    __shared__ __align__(16) f16   cur_lds[32 * 32];
    __shared__ __align__(16) float bias_lds[288];

    const int tid  = threadIdx.x;
    const int wave = tid >> 6;
    const int lane = tid & 63;
    const int n    = lane & 15;
    const int q    = lane >> 4;
    const int n7   = n & 7;
    const int mrow = 32 * wave;
    const int l3g  = wave & 1;
    const int l3h  = wave >> 1;
    const int b0   = blockIdx.x * 2;

    if (tid < 128) bias_lds[tid] = b1[tid];
    else           bias_lds[tid] = b2[tid - 128];
    if (tid < 32)  bias_lds[256 + tid] = b3[tid];

    f16x8 A1[2][3], A2[2][4], A3[4];
#pragma unroll
    for (int mt = 0; mt < 2; ++mt)
#pragma unroll
        for (int ks = 0; ks < 3; ++ks)
            A1[mt][ks] = *(const f16x8*)(W1t + (size_t)(mrow + 16 * mt + n) * 96 + 32 * ks + 8 * q);
#pragma unroll
    for (int mt = 0; mt < 2; ++mt)
#pragma unroll
        for (int ks = 0; ks < 4; ++ks)
            A2[mt][ks] = *(const f16x8*)(W2t + (size_t)(mrow + 16 * mt + n) * 128 + 32 * ks + 8 * q);
#pragma unroll
    for (int ks = 0; ks < 4; ++ks)
        A3[ks] = *(const f16x8*)(W3t + (size_t)(16 * l3h + n) * 128 + 32 * ks + 8 * q);

    LGKM0; __builtin_amdgcn_s_barrier();

    int nlev = 16, lg = 4, fo = 992;
    for (int lev = 0; lev < 5; ++lev) {
        const int rows_t = 2 * nlev;
        f32x4 fa[2], fb[2];
        f16x8 cl[2], cr[2];
#pragma unroll
        for (int g = 0; g < 2; ++g) {
            int r   = 16 * g + n;
            int sel = (r >> lg) & 1;
            int i   = r & (nlev - 1);
            int rc  = sel * nlev + i;
            const float* frow = feats + ((size_t)(b0 + sel) * 1023 + fo + i) * 32;
            fa[g] = *(const f32x4*)(frow + 8 * q);
            fb[g] = *(const f32x4*)(frow + 8 * q + 4);
            if (lev == 0) {
                int gr = (b0 + sel) * 16 + i;
                cl[g] = *(const f16x8*)(cur_in + (size_t)(2 * gr) * 32 + 8 * q);
                cr[g] = *(const f16x8*)(cur_in + (size_t)(2 * gr) * 32 + 32 + 8 * q);
            } else {
                cl[g] = *(const f16x8*)&cur_lds[(2 * rc) * 32 + 8 * q];
                cr[g] = *(const f16x8*)&cur_lds[(2 * rc) * 32 + 32 + 8 * q];
            }
        }
        {
            f32x4 C[2][2];
#pragma unroll
            for (int mt = 0; mt < 2; ++mt) {
                f32x4 bv = *(const f32x4*)&bias_lds[mrow + 16 * mt + 4 * q];
                C[0][mt] = bv; C[1][mt] = bv;
            }
#pragma unroll
            for (int g = 0; g < 2; ++g) {
                f16x8 Bf;
#pragma unroll
                for (int j = 0; j < 4; ++j) { Bf[j] = (f16)fa[g][j]; Bf[4 + j] = (f16)fb[g][j]; }
#pragma unroll
                for (int mt = 0; mt < 2; ++mt) C[g][mt] = MFMA16(A1[mt][0], Bf, C[g][mt]);
#pragma unroll
                for (int mt = 0; mt < 2; ++mt) C[g][mt] = MFMA16(A1[mt][1], cl[g], C[g][mt]);
#pragma unroll
                for (int mt = 0; mt < 2; ++mt) C[g][mt] = MFMA16(A1[mt][2], cr[g], C[g][mt]);
            }
#pragma unroll
            for (int g = 0; g < 2; ++g)
#pragma unroll
                for (int mt = 0; mt < 2; ++mt) {
                    f16x4 pk;
                    pk[0] = (f16)fmaxf(C[g][mt][0], 0.0f);
                    pk[1] = (f16)fmaxf(C[g][mt][1], 0.0f);
                    pk[2] = (f16)fmaxf(C[g][mt][2], 0.0f);
                    pk[3] = (f16)fmaxf(C[g][mt][3], 0.0f);
                    const int ch = 4 * wave + 2 * mt + (q >> 1);
                    *(f16x4*)&h1[(16 * g + n) * 128 + ((ch ^ n7) << 3) + 4 * (q & 1)] = pk;
                }
        }
        LGKM0; __builtin_amdgcn_s_barrier();
        {
            f32x4 C[2][2];
#pragma unroll
            for (int mt = 0; mt < 2; ++mt) {
                f32x4 bv = *(const f32x4*)&bias_lds[128 + mrow + 16 * mt + 4 * q];
                C[0][mt] = bv; C[1][mt] = bv;
            }
#pragma unroll
            for (int ks = 0; ks < 4; ++ks)
#pragma unroll
                for (int g = 0; g < 2; ++g) {
                    f16x8 Bf = *(const f16x8*)&h1[(16 * g + n) * 128 + (((4 * ks + q) ^ n7) << 3)];
#pragma unroll
                    for (int mt = 0; mt < 2; ++mt) C[g][mt] = MFMA16(A2[mt][ks], Bf, C[g][mt]);
                }
#pragma unroll
            for (int g = 0; g < 2; ++g)
#pragma unroll
                for (int mt = 0; mt < 2; ++mt) {
                    f16x4 pk;
                    pk[0] = (f16)fmaxf(C[g][mt][0], 0.0f);
                    pk[1] = (f16)fmaxf(C[g][mt][1], 0.0f);
                    pk[2] = (f16)fmaxf(C[g][mt][2], 0.0f);
                    pk[3] = (f16)fmaxf(C[g][mt][3], 0.0f);
                    const int ch = 4 * wave + 2 * mt + (q >> 1);
                    *(f16x4*)&h2[(16 * g + n) * 128 + ((ch ^ n7) << 3) + 4 * (q & 1)] = pk;
                }
        }
        LGKM0; __builtin_amdgcn_s_barrier();
        {
            f32x4 C3 = *(const f32x4*)&bias_lds[256 + 16 * l3h + 4 * q];
#pragma unroll
            for (int ks = 0; ks < 4; ++ks) {
                f16x8 Bf = *(const f16x8*)&h2[(16 * l3g + n) * 128 + (((4 * ks + q) ^ n7) << 3)];
                C3 = MFMA16(A3[ks], Bf, C3);
            }
            if (nlev > 1) {
                int row = 16 * l3g + n;
                if (row < rows_t) {
                    f16x4 pk;
                    pk[0] = (f16)C3[0]; pk[1] = (f16)C3[1]; pk[2] = (f16)C3[2]; pk[3] = (f16)C3[3];
                    *(f16x4*)&cur_lds[row * 32 + 16 * l3h + 4 * q] = pk;
                }
            } else {
                if (l3g == 0 && l3h == 0 && q == 0 && n < 2)
                    out_final[b0 + n] = C3[0];
            }
        }
        LGKM0; __builtin_amdgcn_s_barrier();
        fo += nlev;
        nlev >>= 1;
        --lg;
    }
}

extern "C" void kernel_launch(void* const* d_in, const int* in_sizes, int n_in,
                              void* d_out, int out_size, void* d_ws, size_t ws_size,
                              hipStream_t stream)
{
    const float* leaf_feats     = (const float*)d_in[0];
    const float* internal_feats = (const float*)d_in[1];
    const float* sW1 = (const float*)d_in[2];  const float* sb1 = (const float*)d_in[3];
    const float* sW2 = (const float*)d_in[4];  const float* sb2 = (const float*)d_in[5];
    const float* sW3 = (const float*)d_in[6];  const float* sb3 = (const float*)d_in[7];
    const float* jW1 = (const float*)d_in[8];  const float* jb1 = (const float*)d_in[9];
    const float* jW2 = (const float*)d_in[10]; const float* jb2 = (const float*)d_in[11];
    const float* jW3 = (const float*)d_in[12]; const float* jb3 = (const float*)d_in[13];

    f16* wbuf = (f16*)d_ws;
    f16* curA = (f16*)((char*)d_ws + CURA_BYTE_OFF);                 // 128 MB
    f16* curB = (f16*)((char*)d_ws + CURA_BYTE_OFF + 134217728);     // 64 MB

    prep_weights<<<(W_TOTAL + 255) / 256, 256, 0, stream>>>(
        sW1, sW2, sW3, jW1, jW2, jW3, wbuf);

    // leaf: 2048*1024 rows = 32768 tiles of 64 rows; grid 2048, nt = 16
    mlp_leaf64<<<2048, 256, 0, stream>>>(
        leaf_feats, curA,
        wbuf + OFF_S1, wbuf + OFF_S2, wbuf + OFF_S3,
        sb1, sb2, sb3,
        16);

    // join levels 512..32 (R3-verified structure)
    const f16* cin = curA;
    f16* cout = curB;
    int off = 0, lg = 9;
    for (int nlev = 512; nlev >= 32; nlev >>= 1, --lg) {
        int rows  = 2048 * nlev;
        int iters = rows / 32;
        int grid  = iters < 2048 ? iters : 2048;
        mlp_join<<<grid, 256, 0, stream>>>(
            internal_feats, cin, cout,
            wbuf + OFF_J1, wbuf + OFF_J2, wbuf + OFF_J3,
            jb1, jb2, jb3,
            rows, lg, off);
        off += nlev;
        f16* t = cout; cout = (f16*)cin; cin = t;
    }

    // fused tail: levels 16..1 (off == 992 here), 2 batches per block
    mlp_tail<<<1024, 256, 0, stream>>>(
        internal_feats, cin, (float*)d_out,
        wbuf + OFF_J1, wbuf + OFF_J2, wbuf + OFF_J3,
        jb1, jb2, jb3);
}